// Round 1
// baseline (403.345 us; speedup 1.0000x reference)
//
#include <hip/hip_runtime.h>
#include <hip/hip_bf16.h>

typedef __attribute__((ext_vector_type(8))) short bf16x8;
typedef __attribute__((ext_vector_type(4))) short bf16x4;
typedef __attribute__((ext_vector_type(4))) float f32x4;

__device__ __forceinline__ short f2bf(float f){
  __hip_bfloat16 h = __float2bfloat16(f);
  return __builtin_bit_cast(short, h);
}
__device__ __forceinline__ float bf2f(short s){
  unsigned u = ((unsigned)(unsigned short)s) << 16;
  return __builtin_bit_cast(float, u);
}

// ---------------- GroupNorm stats: one block per (batch, group) ----------------
__global__ __launch_bounds__(256) void gn_stats(const float* __restrict__ x,
                                                float* __restrict__ stats){
  int b = blockIdx.x >> 5, g = blockIdx.x & 31;
  const float4* p = (const float4*)(x + ((long long)b*512 + g*16)*4096);
  float s = 0.f, s2 = 0.f;
  for (int i = threadIdx.x; i < 16384; i += 256){
    float4 v = p[i];
    s  += v.x + v.y + v.z + v.w;
    s2 += v.x*v.x + v.y*v.y + v.z*v.z + v.w*v.w;
  }
  #pragma unroll
  for (int o = 32; o; o >>= 1){ s += __shfl_xor(s, o); s2 += __shfl_xor(s2, o); }
  __shared__ float rs[4], rs2[4];
  int wid = threadIdx.x >> 6;
  if ((threadIdx.x & 63) == 0){ rs[wid] = s; rs2[wid] = s2; }
  __syncthreads();
  if (threadIdx.x == 0){
    float S  = rs[0]+rs[1]+rs[2]+rs[3];
    float S2 = rs2[0]+rs2[1]+rs2[2]+rs2[3];
    float mean = S * (1.f/65536.f);
    float var  = S2 * (1.f/65536.f) - mean*mean;
    stats[blockIdx.x*2]   = mean;
    stats[blockIdx.x*2+1] = rsqrtf(var + 1e-6f);
  }
}

// ------------- GN apply + transpose [B,C,N] -> h bf16 [B,N,C] ------------------
__global__ __launch_bounds__(256) void gn_apply(const float* __restrict__ x,
                                                const float* __restrict__ stats,
                                                const float* __restrict__ gw,
                                                const float* __restrict__ gb,
                                                short* __restrict__ h){
  __shared__ float tile[128][65];
  int b  = blockIdx.y;
  int n0 = blockIdx.x * 64;
  int t  = threadIdx.x;
  const float* xb = x + (long long)b*512*4096;
  for (int cc = 0; cc < 4; cc++){
    int c0 = cc*128;
    #pragma unroll
    for (int r = 0; r < 128; r += 4){
      int c = r + (t >> 6);
      tile[c][t & 63] = xb[(long long)(c0+c)*4096 + n0 + (t & 63)];
    }
    __syncthreads();
    int n = t >> 2, cp = (t & 3)*32;
    short tmp[32];
    #pragma unroll
    for (int j = 0; j < 32; j++){
      int c = c0 + cp + j;
      float mean = stats[(b*32 + (c >> 4))*2];
      float rstd = stats[(b*32 + (c >> 4))*2 + 1];
      float v = (tile[cp+j][n] - mean)*rstd*gw[c] + gb[c];
      tmp[j] = f2bf(v);
    }
    long long ho = ((long long)b*4096 + n0 + n)*512 + c0 + cp;
    #pragma unroll
    for (int j2 = 0; j2 < 4; j2++){
      bf16x8 v8;
      #pragma unroll
      for (int e = 0; e < 8; e++) v8[e] = tmp[j2*8 + e];
      *(bf16x8*)&h[ho + j2*8] = v8;
    }
    __syncthreads();
  }
}

// ---------------- fp32 -> bf16 weight conversion (exact 262144 elems) ----------
__global__ __launch_bounds__(256) void f2bf_kernel(const float* __restrict__ in,
                                                   short* __restrict__ out){
  int i = blockIdx.x*256 + threadIdx.x;
  const float4* p = (const float4*)in + (long long)i*2;
  float4 a = p[0], c = p[1];
  bf16x8 v;
  v[0]=f2bf(a.x); v[1]=f2bf(a.y); v[2]=f2bf(a.z); v[3]=f2bf(a.w);
  v[4]=f2bf(c.x); v[5]=f2bf(c.y); v[6]=f2bf(c.z); v[7]=f2bf(c.w);
  *(bf16x8*)&out[(long long)i*8] = v;
}

// ---------------- row softmax in place over bf16 rows of length 4096 -----------
__global__ __launch_bounds__(256) void softmax_rows(short* __restrict__ S){
  long long row = blockIdx.x;
  short* p = S + row*4096;
  int t = threadIdx.x;
  bf16x8 v0 = *(bf16x8*)&p[t*16];
  bf16x8 v1 = *(bf16x8*)&p[t*16 + 8];
  float f[16];
  #pragma unroll
  for (int e = 0; e < 8; e++){ f[e] = bf2f(v0[e]); f[8+e] = bf2f(v1[e]); }
  float m = f[0];
  #pragma unroll
  for (int e = 1; e < 16; e++) m = fmaxf(m, f[e]);
  #pragma unroll
  for (int o = 32; o; o >>= 1) m = fmaxf(m, __shfl_xor(m, o));
  __shared__ float red[4];
  int wid = t >> 6;
  if ((t & 63) == 0) red[wid] = m;
  __syncthreads();
  m = fmaxf(fmaxf(red[0], red[1]), fmaxf(red[2], red[3]));
  float s = 0.f;
  #pragma unroll
  for (int e = 0; e < 16; e++){ f[e] = exp2f((f[e]-m)*1.4426950408889634f); s += f[e]; }
  #pragma unroll
  for (int o = 32; o; o >>= 1) s += __shfl_xor(s, o);
  __syncthreads();
  if ((t & 63) == 0) red[wid] = s;
  __syncthreads();
  s = red[0]+red[1]+red[2]+red[3];
  float inv = 1.f/s;
  #pragma unroll
  for (int e = 0; e < 8; e++){ v0[e] = f2bf(f[e]*inv); v1[e] = f2bf(f[8+e]*inv); }
  *(bf16x8*)&p[t*16]     = v0;
  *(bf16x8*)&p[t*16 + 8] = v1;
}

// ---------------- bf16 GEMM: C = (A . B^T + bias) * scale ----------------------
// A [M][Kd] bf16 row-major; B [Nn][Kd] bf16 row-major.
// MODE 0: bf16 out [M][Nn] (LDS-repacked coalesced stores)
// MODE 1: bf16 out transposed [Nn][M]
// MODE 2: fp32 out [Nn][M] with residual add (O-projection epilogue)
#define LDSP 40

template<int MODE>
__global__ __launch_bounds__(256) void gemm_bt(
    const short* __restrict__ A, const short* __restrict__ Bw,
    const float* __restrict__ bias,
    void* __restrict__ outp, const float* __restrict__ resid,
    int M, int Nn, int Kd,
    long long sA, long long sB, long long sO, float scale)
{
  __shared__ short lds[2*128*LDSP];
  short* As = lds;
  short* Bs = lds + 128*LDSP;

  int bz = blockIdx.z;
  const short* Ab = A + bz*sA;
  const short* Bb = Bw + bz*sB;

  int m0 = blockIdx.x*128, n0 = blockIdx.y*128;
  int t = threadIdx.x;
  int wid = t >> 6, lane = t & 63, g = lane >> 4, lr = lane & 15;
  int wr = wid >> 1, wc = wid & 1;

  int srow = t >> 1;
  int sko  = (t & 1)*16;
  const short* pa = Ab + (long long)(m0+srow)*Kd + sko;
  const short* pb = Bb + (long long)(n0+srow)*Kd + sko;

  f32x4 acc[4][4];
  #pragma unroll
  for (int i = 0; i < 4; i++)
    #pragma unroll
    for (int j = 0; j < 4; j++)
      acc[i][j] = f32x4{0.f,0.f,0.f,0.f};

  bf16x8 ra0 = *(const bf16x8*)pa;
  bf16x8 ra1 = *(const bf16x8*)(pa + 8);
  bf16x8 rb0 = *(const bf16x8*)pb;
  bf16x8 rb1 = *(const bf16x8*)(pb + 8);

  int aoff = srow*LDSP + sko;
  for (int kt = 0; kt < Kd; kt += 32){
    *(bf16x8*)&As[aoff]     = ra0;
    *(bf16x8*)&As[aoff + 8] = ra1;
    *(bf16x8*)&Bs[aoff]     = rb0;
    *(bf16x8*)&Bs[aoff + 8] = rb1;
    __syncthreads();
    if (kt + 32 < Kd){
      ra0 = *(const bf16x8*)(pa + kt + 32);
      ra1 = *(const bf16x8*)(pa + kt + 40);
      rb0 = *(const bf16x8*)(pb + kt + 32);
      rb1 = *(const bf16x8*)(pb + kt + 40);
    }
    bf16x8 af[4], bfr[4];
    #pragma unroll
    for (int mi = 0; mi < 4; mi++)
      af[mi] = *(bf16x8*)&As[(wr*64 + mi*16 + lr)*LDSP + g*8];
    #pragma unroll
    for (int ni = 0; ni < 4; ni++)
      bfr[ni] = *(bf16x8*)&Bs[(wc*64 + ni*16 + lr)*LDSP + g*8];
    #pragma unroll
    for (int mi = 0; mi < 4; mi++)
      #pragma unroll
      for (int ni = 0; ni < 4; ni++)
        acc[mi][ni] = __builtin_amdgcn_mfma_f32_16x16x32_bf16(af[mi], bfr[ni], acc[mi][ni], 0, 0, 0);
    __syncthreads();
  }

  if (MODE == 0){
    short* outb = (short*)outp + bz*sO;
    #pragma unroll
    for (int half = 0; half < 2; half++){
      __syncthreads();
      if (wr == half){
        #pragma unroll
        for (int ni = 0; ni < 4; ni++){
          int col = wc*64 + ni*16 + lr;
          float bv2 = bias ? bias[n0 + col] : 0.f;
          #pragma unroll
          for (int mi = 0; mi < 4; mi++){
            #pragma unroll
            for (int i = 0; i < 4; i++){
              int rl = mi*16 + g*4 + i;
              lds[rl*136 + col] = f2bf((acc[mi][ni][i] + bv2)*scale);
            }
          }
        }
      }
      __syncthreads();
      int rl = t >> 2, ccw = (t & 3)*32;
      long long gro = (long long)(m0 + half*64 + rl)*Nn + n0 + ccw;
      bf16x8* dst = (bf16x8*)&outb[gro];
      bf16x8* srcp = (bf16x8*)&lds[rl*136 + ccw];
      dst[0] = srcp[0]; dst[1] = srcp[1]; dst[2] = srcp[2]; dst[3] = srcp[3];
    }
  } else if (MODE == 1){
    short* outb = (short*)outp + bz*sO;
    #pragma unroll
    for (int ni = 0; ni < 4; ni++){
      int col = n0 + wc*64 + ni*16 + lr;
      float bv2 = bias ? bias[col] : 0.f;
      #pragma unroll
      for (int mi = 0; mi < 4; mi++){
        int row = m0 + wr*64 + mi*16 + g*4;
        bf16x4 pk;
        #pragma unroll
        for (int i = 0; i < 4; i++) pk[i] = f2bf((acc[mi][ni][i] + bv2)*scale);
        *(bf16x4*)&outb[(long long)col*M + row] = pk;
      }
    }
  } else {
    float* outb = (float*)outp + bz*sO;
    const float* rx = resid + bz*sO;
    #pragma unroll
    for (int ni = 0; ni < 4; ni++){
      int col = n0 + wc*64 + ni*16 + lr;
      float bv2 = bias[col];
      #pragma unroll
      for (int mi = 0; mi < 4; mi++){
        int row = m0 + wr*64 + mi*16 + g*4;
        long long off = (long long)col*M + row;
        float4 xr = *(const float4*)&rx[off];
        float4 o;
        o.x = acc[mi][ni][0] + bv2 + xr.x;
        o.y = acc[mi][ni][1] + bv2 + xr.y;
        o.z = acc[mi][ni][2] + bv2 + xr.z;
        o.w = acc[mi][ni][3] + bv2 + xr.w;
        *(float4*)&outb[off] = o;
      }
    }
  }
}

extern "C" void kernel_launch(void* const* d_in, const int* in_sizes, int n_in,
                              void* d_out, int out_size, void* d_ws, size_t ws_size,
                              hipStream_t stream)
{
  const float* x   = (const float*)d_in[0];
  const float* gnw = (const float*)d_in[1];
  const float* gnb = (const float*)d_in[2];
  const float* Wq  = (const float*)d_in[3];
  const float* bq  = (const float*)d_in[4];
  const float* Wk  = (const float*)d_in[5];
  const float* bk  = (const float*)d_in[6];
  const float* Wv  = (const float*)d_in[7];
  const float* bvp = (const float*)d_in[8];
  const float* Wo  = (const float*)d_in[9];
  const float* bo  = (const float*)d_in[10];
  float* out = (float*)d_out;

  char* ws = (char*)d_ws;
  const size_t MB = 1ull << 20;
  short* h    = (short*)(ws);
  short* q    = (short*)(ws + 16*MB);
  short* kmat = (short*)(ws + 32*MB);
  short* vt   = (short*)(ws + 48*MB);
  short* ao   = (short*)(ws + 64*MB);
  short* wqb  = (short*)(ws + 80*MB);
  short* wkb  = wqb + 262144;
  short* wvb  = wkb + 262144;
  short* wob  = wvb + 262144;
  float* stats= (float*)(ws + 82*MB);
  short* S    = (short*)(ws + 84*MB);   // 128 MB (full path)

  dim3 blk(256);
  gn_stats<<<dim3(128), blk, 0, stream>>>(x, stats);
  gn_apply<<<dim3(64,4), blk, 0, stream>>>(x, stats, gnw, gnb, h);
  f2bf_kernel<<<dim3(128), blk, 0, stream>>>(Wq, wqb);
  f2bf_kernel<<<dim3(128), blk, 0, stream>>>(Wk, wkb);
  f2bf_kernel<<<dim3(128), blk, 0, stream>>>(Wv, wvb);
  f2bf_kernel<<<dim3(128), blk, 0, stream>>>(Wo, wob);

  const long long sTok = 4096ll*512;
  const float qscale = 0.044194173824159216f;  // 1/sqrt(512)

  // Q (scale folded), K, V(transposed out)
  gemm_bt<0><<<dim3(32,4,4),  blk, 0, stream>>>(h, wqb, bq,  q,    nullptr, 4096, 512, 512, sTok, 0, sTok, qscale);
  gemm_bt<0><<<dim3(32,4,4),  blk, 0, stream>>>(h, wkb, bk,  kmat, nullptr, 4096, 512, 512, sTok, 0, sTok, 1.f);
  gemm_bt<1><<<dim3(32,4,4),  blk, 0, stream>>>(h, wvb, bvp, vt,   nullptr, 4096, 512, 512, sTok, 0, sTok, 1.f);

  if (ws_size >= 212*MB){
    gemm_bt<0><<<dim3(32,32,4), blk, 0, stream>>>(q, kmat, nullptr, S, nullptr, 4096, 4096, 512, sTok, sTok, 4096ll*4096, 1.f);
    softmax_rows<<<dim3(16384), blk, 0, stream>>>(S);
    gemm_bt<0><<<dim3(32,4,4),  blk, 0, stream>>>(S, vt, nullptr, ao, nullptr, 4096, 512, 4096, 4096ll*4096, sTok, sTok, 1.f);
  } else {
    // per-batch fallback: S slab reused, needs only 84MB + 32MB of ws
    for (int b = 0; b < 4; b++){
      gemm_bt<0><<<dim3(32,32,1), blk, 0, stream>>>(q + b*sTok, kmat + b*sTok, nullptr, S, nullptr, 4096, 4096, 512, 0, 0, 0, 1.f);
      softmax_rows<<<dim3(4096), blk, 0, stream>>>(S);
      gemm_bt<0><<<dim3(32,4,1),  blk, 0, stream>>>(S, vt + b*sTok, nullptr, ao + b*sTok, nullptr, 4096, 512, 4096, 0, 0, 0, 1.f);
    }
  }

  // O-projection + bias + residual + transpose to [B, C, N] fp32
  gemm_bt<2><<<dim3(32,4,4), blk, 0, stream>>>(ao, wob, bo, out, x, 4096, 512, 512, sTok, 0, sTok, 1.f);
}